// Round 4
// baseline (124.488 us; speedup 1.0000x reference)
//
#include <hip/hip_runtime.h>

#define D_IN   1024
#define D_PROJ 256
#define N_C    64
#define N_ROWS 16384
#define BM     64
#define Z_STRIDE 264    // D_PROJ + 8 pad -> rotates chunk->bank map by 1 per row

typedef float v4f __attribute__((ext_vector_type(4)));
typedef short v8s __attribute__((ext_vector_type(8)));

__device__ inline unsigned short f2bf(float f) {
  unsigned int u = __float_as_uint(f);
  u = u + 0x7fffu + ((u >> 16) & 1u);   // round-to-nearest-even
  return (unsigned short)(u >> 16);
}

// ---------------------------------------------------------------------------
// Prep: projT bf16 [256][1024] (transposed), protoB bf16 [64][256], pnorm2[64],
//       mu_p[256] = mean @ proj (fp32)
// grid 96 x 256: blocks 0..63 transpose, 64..79 protos, 80..95 mu_p
// ---------------------------------------------------------------------------
__global__ __launch_bounds__(256) void prep_kernel(
    const float* __restrict__ proj,      // [1024][256]
    const float* __restrict__ protos,    // [64][256]
    const float* __restrict__ mean,      // [1024]
    unsigned short* __restrict__ projT,  // [256][1024]
    unsigned short* __restrict__ protoB, // [64][256]
    float* __restrict__ pnorm2,          // [64]
    float* __restrict__ mu_p)            // [256]
{
  __shared__ float tile[64][65];
  __shared__ float part[16][17];
  const int b = blockIdx.x;
  const int t = threadIdx.x;
  if (b < 64) {
    const int k0 = (b & 15) * 64, n0 = (b >> 4) * 64;
    const int r = t >> 4, c4 = (t & 15) * 4;
    for (int rr = r; rr < 64; rr += 16) {
      const float4 v = *(const float4*)(proj + (k0 + rr) * D_PROJ + n0 + c4);
      tile[rr][c4 + 0] = v.x; tile[rr][c4 + 1] = v.y;
      tile[rr][c4 + 2] = v.z; tile[rr][c4 + 3] = v.w;
    }
    __syncthreads();
    const int n = t >> 2, kc = (t & 3) * 16;
    unsigned short o[16];
#pragma unroll
    for (int i = 0; i < 16; ++i) o[i] = f2bf(tile[kc + i][n]);
    unsigned short* dst = projT + (n0 + n) * D_IN + k0 + kc;
#pragma unroll
    for (int i = 0; i < 4; ++i) {
      ushort4 s4 = { o[4*i+0], o[4*i+1], o[4*i+2], o[4*i+3] };
      *(ushort4*)(dst + 4*i) = s4;
    }
  } else if (b < 80) {
    const int w = t >> 6, l = t & 63;
    const int c = (b - 64) * 4 + w;                    // proto 0..63
    const float4 v = *(const float4*)(protos + c * D_PROJ + l * 4);
    float ss = v.x*v.x + v.y*v.y + v.z*v.z + v.w*v.w;
#pragma unroll
    for (int m = 1; m < 64; m <<= 1) ss += __shfl_xor(ss, m);
    if (l == 0) pnorm2[c] = ss;
    ushort4 o = { f2bf(v.x), f2bf(v.y), f2bf(v.z), f2bf(v.w) };
    *(ushort4*)(protoB + c * D_PROJ + l * 4) = o;
  } else {
    // mu_p: 16 blocks x 16 cols each; 16-way k-split per col
    const int b2  = b - 80;
    const int col = b2 * 16 + (t & 15);
    const int ks  = t >> 4;
    float s = 0.0f;
    const int kb = ks * 64;
#pragma unroll 4
    for (int k = 0; k < 64; ++k)
      s = fmaf(mean[kb + k], proj[(kb + k) * D_PROJ + col], s);
    part[ks][t & 15] = s;
    __syncthreads();
    if (t < 16) {
      float acc = 0.0f;
#pragma unroll
      for (int i = 0; i < 16; ++i) acc += part[i][t];
      mu_p[b2 * 16 + t] = acc;
    }
  }
}

// ---------------------------------------------------------------------------
// Main fused kernel: 64 rows/block, 256 blocks (1/CU), 512 threads (8 waves).
// BARRIER-FREE K-loop (AITER pattern): full A block staged once into LDS
// (XOR-swizzled), B fragments stream global->VGPR from L2-resident projT.
// Wave w owns a disjoint 32-col group -> projT read exactly once per block.
// ---------------------------------------------------------------------------
__global__ __launch_bounds__(512, 2) void protonet_main(
    const float* __restrict__ X,               // [16384][1024]
    const unsigned short* __restrict__ projT,  // [256][1024] bf16
    const unsigned short* __restrict__ protoB, // [64][256]   bf16
    const float* __restrict__ pnorm2,          // [64]
    const float* __restrict__ mu_p,            // [256]
    float* __restrict__ out)                   // [16384][64]
{
  __shared__ unsigned short lds_A[BM * D_IN];   // 128 KB; aliased as Z later
  __shared__ float lds_part[8][BM];             // 2 KB
  __shared__ float lds_inv[BM];
  __shared__ float lds_z2[BM];

  const int t  = threadIdx.x;
  const int w  = t >> 6;      // wave 0..7
  const int l  = t & 63;
  const int q  = l >> 4;
  const int lc = l & 15;
  const int cb = w << 5;      // this wave's 32-col group
  const int row0 = blockIdx.x * BM;

  // ---- stage A: X fp32 -> bf16, 16B chunks XOR-swizzled by (row&7) ----
  // thread t: rows 4i + (t>>7), chunk (t&127); 32 float4 loads in flight.
  const int rbase = t >> 7;
  const int cw    = t & 127;
  float4 xa[16], xb[16];
#pragma unroll
  for (int i = 0; i < 16; ++i) {
    const float* p = X + (size_t)(row0 + (i << 2) + rbase) * D_IN + (cw << 3);
    xa[i] = *(const float4*)p;
    xb[i] = *(const float4*)(p + 4);
  }
  // wave-col mu (issued early; consumed after GEMM1)
  const float mu0 = mu_p[cb + lc];
  const float mu1 = mu_p[cb + 16 + lc];
#pragma unroll
  for (int i = 0; i < 16; ++i) {
    const int row  = (i << 2) + rbase;
    const int phys = cw ^ (row & 7);
    v8s o = { (short)f2bf(xa[i].x), (short)f2bf(xa[i].y),
              (short)f2bf(xa[i].z), (short)f2bf(xa[i].w),
              (short)f2bf(xb[i].x), (short)f2bf(xb[i].y),
              (short)f2bf(xb[i].z), (short)f2bf(xb[i].w) };
    *(v8s*)(lds_A + row * D_IN + (phys << 3)) = o;
  }
  __syncthreads();   // the ONLY barrier before GEMM1

  // ---- GEMM1: 64 rows x 32 cols per wave, K=1024, no barriers ----
  v4f acc1[4][2];
#pragma unroll
  for (int i = 0; i < 4; ++i) { acc1[i][0] = (v4f)(0.0f); acc1[i][1] = (v4f)(0.0f); }

  const unsigned short* bp0 = projT + (size_t)(cb + lc) * D_IN + (q << 3);
  const unsigned short* bp1 = bp0 + 16 * D_IN;
  const unsigned short* ap  = lds_A + lc * D_IN;

#pragma unroll 4
  for (int kk = 0; kk < 32; ++kk) {
    const v8s b0 = *(const v8s*)(bp0 + (kk << 5));
    const v8s b1 = *(const v8s*)(bp1 + (kk << 5));
    const int phys = (((kk << 2) + q) ^ (lc & 7)) << 3;
    const v8s a0 = *(const v8s*)(ap + phys);
    const v8s a1 = *(const v8s*)(ap + 16 * D_IN + phys);
    const v8s a2 = *(const v8s*)(ap + 32 * D_IN + phys);
    const v8s a3 = *(const v8s*)(ap + 48 * D_IN + phys);
    acc1[0][0] = __builtin_amdgcn_mfma_f32_16x16x32_bf16(a0, b0, acc1[0][0], 0, 0, 0);
    acc1[0][1] = __builtin_amdgcn_mfma_f32_16x16x32_bf16(a0, b1, acc1[0][1], 0, 0, 0);
    acc1[1][0] = __builtin_amdgcn_mfma_f32_16x16x32_bf16(a1, b0, acc1[1][0], 0, 0, 0);
    acc1[1][1] = __builtin_amdgcn_mfma_f32_16x16x32_bf16(a1, b1, acc1[1][1], 0, 0, 0);
    acc1[2][0] = __builtin_amdgcn_mfma_f32_16x16x32_bf16(a2, b0, acc1[2][0], 0, 0, 0);
    acc1[2][1] = __builtin_amdgcn_mfma_f32_16x16x32_bf16(a2, b1, acc1[2][1], 0, 0, 0);
    acc1[3][0] = __builtin_amdgcn_mfma_f32_16x16x32_bf16(a3, b0, acc1[3][0], 0, 0, 0);
    acc1[3][1] = __builtin_amdgcn_mfma_f32_16x16x32_bf16(a3, b1, acc1[3][1], 0, 0, 0);
  }

  __syncthreads();   // all A reads done -> reuse lds_A as Z
  unsigned short* lds_Z = lds_A;

  // ---- Zc = Zraw - mu_p -> LDS bf16 (padded stride) + fp32 row norms ----
#pragma unroll
  for (int i = 0; i < 4; ++i) {
#pragma unroll
    for (int r = 0; r < 4; ++r) {
      const int row = (i << 4) + (q << 2) + r;
      const float v0 = acc1[i][0][r] - mu0;
      const float v1 = acc1[i][1][r] - mu1;
      float s2 = v0 * v0 + v1 * v1;
      lds_Z[row * Z_STRIDE + cb + lc]      = f2bf(v0);
      lds_Z[row * Z_STRIDE + cb + 16 + lc] = f2bf(v1);
      s2 += __shfl_xor(s2, 1);
      s2 += __shfl_xor(s2, 2);
      s2 += __shfl_xor(s2, 4);
      s2 += __shfl_xor(s2, 8);
      if (lc == 0) lds_part[w][row] = s2;
    }
  }
  __syncthreads();
  if (t < BM) {
    float n2 = 0.0f;
#pragma unroll
    for (int i = 0; i < 8; ++i) n2 += lds_part[i][t];
    const float nrm = sqrtf(n2);
    const float inv = 1.0f / fmaxf(nrm, 1e-12f);   // torch/jax normalize eps
    lds_inv[t] = inv;
    lds_z2[t]  = n2 * inv * inv;                   // == 1 unless degenerate
  }
  __syncthreads();

  // ---- GEMM2: dot(Zc, proto); wave w -> rows 16*(w>>1), protos 32*(w&1) ----
  const int rg  = w >> 1;          // 0..3 row group
  const int pg0 = (w & 1) << 1;    // proto groups pg0, pg0+1
  v4f acc2[2];
  acc2[0] = (v4f)(0.0f); acc2[1] = (v4f)(0.0f);
  const unsigned short* zp  = lds_Z + ((rg << 4) + lc) * Z_STRIDE + (q << 3);
  const unsigned short* pp0 = protoB + (size_t)((pg0 << 4) + lc) * D_PROJ + (q << 3);
  const unsigned short* pp1 = pp0 + 16 * D_PROJ;
#pragma unroll
  for (int kk = 0; kk < 8; ++kk) {
    const v8s za = *(const v8s*)(zp  + (kk << 5));
    const v8s p0 = *(const v8s*)(pp0 + (kk << 5));
    const v8s p1 = *(const v8s*)(pp1 + (kk << 5));
    acc2[0] = __builtin_amdgcn_mfma_f32_16x16x32_bf16(za, p0, acc2[0], 0, 0, 0);
    acc2[1] = __builtin_amdgcn_mfma_f32_16x16x32_bf16(za, p1, acc2[1], 0, 0, 0);
  }

  // ---- epilogue: d^2 = ||Z||^2 + ||p||^2 - 2*dot*inv ; score = -sqrt(d^2) ----
  const float pn0 = pnorm2[(pg0 << 4) + lc];
  const float pn1 = pnorm2[(pg0 << 4) + 16 + lc];
#pragma unroll
  for (int r = 0; r < 4; ++r) {
    const int row = (rg << 4) + (q << 2) + r;
    const float inv = lds_inv[row];
    const float z2  = lds_z2[row];
    const float d0 = z2 + pn0 - 2.0f * acc2[0][r] * inv;
    const float d1 = z2 + pn1 - 2.0f * acc2[1][r] * inv;
    float* ob = out + (size_t)(row0 + row) * N_C + (pg0 << 4) + lc;
    ob[0]  = -sqrtf(fmaxf(d0, 0.0f));
    ob[16] = -sqrtf(fmaxf(d1, 0.0f));
  }
}

extern "C" void kernel_launch(void* const* d_in, const int* in_sizes, int n_in,
                              void* d_out, int out_size, void* d_ws, size_t ws_size,
                              hipStream_t stream) {
  const float* X      = (const float*)d_in[0];
  const float* protos = (const float*)d_in[1];
  const float* mean   = (const float*)d_in[2];
  const float* proj   = (const float*)d_in[3];
  float* out = (float*)d_out;

  unsigned short* projT  = (unsigned short*)d_ws;          // 256*1024 bf16 = 512 KB
  unsigned short* protoB = projT + D_PROJ * D_IN;          // 64*256  bf16 = 32 KB
  float*          pn2    = (float*)(protoB + N_C * D_PROJ);// 64 fp32
  float*          mup    = pn2 + N_C;                      // 256 fp32

  prep_kernel<<<96, 256, 0, stream>>>(proj, protos, mean, projT, protoB, pn2, mup);
  protonet_main<<<N_ROWS / BM, 512, 0, stream>>>(X, projT, protoB, pn2, mup, out);
}

// Round 5
// 123.247 us; speedup vs baseline: 1.0101x; 1.0101x over previous
//
#include <hip/hip_runtime.h>

#define D_IN   1024
#define D_PROJ 256
#define N_C    64
#define N_ROWS 16384
#define BM     64
#define Z_STRIDE 264    // D_PROJ + 8 pad

typedef float v4f __attribute__((ext_vector_type(4)));
typedef short v8s __attribute__((ext_vector_type(8)));

__device__ inline unsigned short f2bf(float f) {
  unsigned int u = __float_as_uint(f);
  u = u + 0x7fffu + ((u >> 16) & 1u);   // round-to-nearest-even
  return (unsigned short)(u >> 16);
}

// ---------------------------------------------------------------------------
// Prep: projT bf16 [256][1024] (transposed), protoB bf16 [64][256], pnorm2[64],
//       mu_p[256] = mean @ proj (fp32)
// grid 96 x 256: blocks 0..63 transpose, 64..79 protos, 80..95 mu_p
// ---------------------------------------------------------------------------
__global__ __launch_bounds__(256) void prep_kernel(
    const float* __restrict__ proj,      // [1024][256]
    const float* __restrict__ protos,    // [64][256]
    const float* __restrict__ mean,      // [1024]
    unsigned short* __restrict__ projT,  // [256][1024]
    unsigned short* __restrict__ protoB, // [64][256]
    float* __restrict__ pnorm2,          // [64]
    float* __restrict__ mu_p)            // [256]
{
  __shared__ float tile[64][65];
  __shared__ float part[16][17];
  const int b = blockIdx.x;
  const int t = threadIdx.x;
  if (b < 64) {
    const int k0 = (b & 15) * 64, n0 = (b >> 4) * 64;
    const int r = t >> 4, c4 = (t & 15) * 4;
    for (int rr = r; rr < 64; rr += 16) {
      const float4 v = *(const float4*)(proj + (k0 + rr) * D_PROJ + n0 + c4);
      tile[rr][c4 + 0] = v.x; tile[rr][c4 + 1] = v.y;
      tile[rr][c4 + 2] = v.z; tile[rr][c4 + 3] = v.w;
    }
    __syncthreads();
    const int n = t >> 2, kc = (t & 3) * 16;
    unsigned short o[16];
#pragma unroll
    for (int i = 0; i < 16; ++i) o[i] = f2bf(tile[kc + i][n]);
    unsigned short* dst = projT + (n0 + n) * D_IN + k0 + kc;
#pragma unroll
    for (int i = 0; i < 4; ++i) {
      ushort4 s4 = { o[4*i+0], o[4*i+1], o[4*i+2], o[4*i+3] };
      *(ushort4*)(dst + 4*i) = s4;
    }
  } else if (b < 80) {
    const int w = t >> 6, l = t & 63;
    const int c = (b - 64) * 4 + w;                    // proto 0..63
    const float4 v = *(const float4*)(protos + c * D_PROJ + l * 4);
    float ss = v.x*v.x + v.y*v.y + v.z*v.z + v.w*v.w;
#pragma unroll
    for (int m = 1; m < 64; m <<= 1) ss += __shfl_xor(ss, m);
    if (l == 0) pnorm2[c] = ss;
    ushort4 o = { f2bf(v.x), f2bf(v.y), f2bf(v.z), f2bf(v.w) };
    *(ushort4*)(protoB + c * D_PROJ + l * 4) = o;
  } else {
    // mu_p: 16 blocks x 16 cols each; 16-way k-split per col
    const int b2  = b - 80;
    const int col = b2 * 16 + (t & 15);
    const int ks  = t >> 4;
    float s = 0.0f;
    const int kb = ks * 64;
#pragma unroll 4
    for (int k = 0; k < 64; ++k)
      s = fmaf(mean[kb + k], proj[(kb + k) * D_PROJ + col], s);
    part[ks][t & 15] = s;
    __syncthreads();
    if (t < 16) {
      float acc = 0.0f;
#pragma unroll
      for (int i = 0; i < 16; ++i) acc += part[i][t];
      mu_p[b2 * 16 + t] = acc;
    }
  }
}

// ---------------------------------------------------------------------------
// Main fused kernel: 64 rows/block, 256 blocks (1/CU), 512 threads (8 waves).
// Barrier-free K-loop; X staged with FORCED full-depth loads (asm vmcnt fence
// prevents the compiler from sinking/batching the 32 global loads), B stream
// double-buffered 4 ksteps ahead from L2-resident projT.
// ---------------------------------------------------------------------------
__global__ __launch_bounds__(512, 2) void protonet_main(
    const float* __restrict__ X,               // [16384][1024]
    const unsigned short* __restrict__ projT,  // [256][1024] bf16
    const unsigned short* __restrict__ protoB, // [64][256]   bf16
    const float* __restrict__ pnorm2,          // [64]
    const float* __restrict__ mu_p,            // [256]
    float* __restrict__ out)                   // [16384][64]
{
  __shared__ unsigned short lds_A[BM * D_IN];   // 128 KB; aliased as Z later
  __shared__ float lds_part[8][BM];             // 2 KB
  __shared__ float lds_inv[BM];
  __shared__ float lds_z2[BM];

  const int t  = threadIdx.x;
  const int w  = t >> 6;      // wave 0..7
  const int l  = t & 63;
  const int q  = l >> 4;
  const int lc = l & 15;
  const int cb = w << 5;      // this wave's 32-col group
  const int row0 = blockIdx.x * BM;

  // ---- stage A: X fp32 -> bf16, 16B chunks XOR-swizzled by (row&7) ----
  const int rbase = t >> 7;
  const int cw    = t & 127;
  float4 xa[16], xb[16];
#pragma unroll
  for (int i = 0; i < 16; ++i) {
    const float* p = X + (size_t)(row0 + (i << 2) + rbase) * D_IN + (cw << 3);
    xa[i] = *(const float4*)p;
    xb[i] = *(const float4*)(p + 4);
  }

  // B stream pointers; pre-issue group 0 so its L2 latency hides under staging
  const unsigned short* bp0 = projT + (size_t)(cb + lc) * D_IN + (q << 3);
  const unsigned short* bp1 = bp0 + 16 * D_IN;
  v8s bb[2][8];
#pragma unroll
  for (int k2 = 0; k2 < 4; ++k2) {
    bb[0][k2 * 2]     = *(const v8s*)(bp0 + (k2 << 5));
    bb[0][k2 * 2 + 1] = *(const v8s*)(bp1 + (k2 << 5));
  }
  const float mu0 = mu_p[cb + lc];
  const float mu1 = mu_p[cb + 16 + lc];

  // force all of the above into flight before anything retires
  asm volatile("s_waitcnt vmcnt(0)" ::: "memory");

#pragma unroll
  for (int i = 0; i < 16; ++i) {
    const int row  = (i << 2) + rbase;
    const int phys = cw ^ (row & 7);
    v8s o = { (short)f2bf(xa[i].x), (short)f2bf(xa[i].y),
              (short)f2bf(xa[i].z), (short)f2bf(xa[i].w),
              (short)f2bf(xb[i].x), (short)f2bf(xb[i].y),
              (short)f2bf(xb[i].z), (short)f2bf(xb[i].w) };
    *(v8s*)(lds_A + row * D_IN + (phys << 3)) = o;
  }
  __syncthreads();   // the ONLY barrier before GEMM1

  // ---- GEMM1: 64 rows x 32 cols per wave, K=1024, no barriers ----
  v4f acc1[4][2];
#pragma unroll
  for (int i = 0; i < 4; ++i) { acc1[i][0] = (v4f)(0.0f); acc1[i][1] = (v4f)(0.0f); }

  const unsigned short* ap = lds_A + lc * D_IN;

#pragma unroll
  for (int g = 0; g < 8; ++g) {
    const int cur = g & 1, nxt = cur ^ 1;
    if (g < 7) {
#pragma unroll
      for (int k2 = 0; k2 < 4; ++k2) {
        bb[nxt][k2 * 2]     = *(const v8s*)(bp0 + ((((g + 1) << 2) + k2) << 5));
        bb[nxt][k2 * 2 + 1] = *(const v8s*)(bp1 + ((((g + 1) << 2) + k2) << 5));
      }
    }
#pragma unroll
    for (int k2 = 0; k2 < 4; ++k2) {
      const int kk = (g << 2) + k2;
      const int phys = (((kk << 2) + q) ^ (lc & 7)) << 3;
      const v8s a0 = *(const v8s*)(ap + phys);
      const v8s a1 = *(const v8s*)(ap + 16 * D_IN + phys);
      const v8s a2 = *(const v8s*)(ap + 32 * D_IN + phys);
      const v8s a3 = *(const v8s*)(ap + 48 * D_IN + phys);
      const v8s b0 = bb[cur][k2 * 2];
      const v8s b1 = bb[cur][k2 * 2 + 1];
      acc1[0][0] = __builtin_amdgcn_mfma_f32_16x16x32_bf16(a0, b0, acc1[0][0], 0, 0, 0);
      acc1[0][1] = __builtin_amdgcn_mfma_f32_16x16x32_bf16(a0, b1, acc1[0][1], 0, 0, 0);
      acc1[1][0] = __builtin_amdgcn_mfma_f32_16x16x32_bf16(a1, b0, acc1[1][0], 0, 0, 0);
      acc1[1][1] = __builtin_amdgcn_mfma_f32_16x16x32_bf16(a1, b1, acc1[1][1], 0, 0, 0);
      acc1[2][0] = __builtin_amdgcn_mfma_f32_16x16x32_bf16(a2, b0, acc1[2][0], 0, 0, 0);
      acc1[2][1] = __builtin_amdgcn_mfma_f32_16x16x32_bf16(a2, b1, acc1[2][1], 0, 0, 0);
      acc1[3][0] = __builtin_amdgcn_mfma_f32_16x16x32_bf16(a3, b0, acc1[3][0], 0, 0, 0);
      acc1[3][1] = __builtin_amdgcn_mfma_f32_16x16x32_bf16(a3, b1, acc1[3][1], 0, 0, 0);
    }
  }

  __syncthreads();   // all A reads done -> reuse lds_A as Z
  unsigned short* lds_Z = lds_A;

  // ---- Zc = Zraw - mu_p -> LDS bf16 (padded stride) + fp32 row norms ----
#pragma unroll
  for (int i = 0; i < 4; ++i) {
#pragma unroll
    for (int r = 0; r < 4; ++r) {
      const int row = (i << 4) + (q << 2) + r;
      const float v0 = acc1[i][0][r] - mu0;
      const float v1 = acc1[i][1][r] - mu1;
      float s2 = v0 * v0 + v1 * v1;
      lds_Z[row * Z_STRIDE + cb + lc]      = f2bf(v0);
      lds_Z[row * Z_STRIDE + cb + 16 + lc] = f2bf(v1);
      s2 += __shfl_xor(s2, 1);
      s2 += __shfl_xor(s2, 2);
      s2 += __shfl_xor(s2, 4);
      s2 += __shfl_xor(s2, 8);
      if (lc == 0) lds_part[w][row] = s2;
    }
  }
  __syncthreads();
  if (t < BM) {
    float n2 = 0.0f;
#pragma unroll
    for (int i = 0; i < 8; ++i) n2 += lds_part[i][t];
    const float nrm = sqrtf(n2);
    const float inv = 1.0f / fmaxf(nrm, 1e-12f);   // torch/jax normalize eps
    lds_inv[t] = inv;
    lds_z2[t]  = n2 * inv * inv;                   // == 1 unless degenerate
  }
  __syncthreads();

  // ---- GEMM2: dot(Zc, proto); wave w -> rows 16*(w>>1), protos 32*(w&1) ----
  const int rg  = w >> 1;          // 0..3 row group
  const int pg0 = (w & 1) << 1;    // proto groups pg0, pg0+1
  v4f acc2[2];
  acc2[0] = (v4f)(0.0f); acc2[1] = (v4f)(0.0f);
  const unsigned short* zp  = lds_Z + ((rg << 4) + lc) * Z_STRIDE + (q << 3);
  const unsigned short* pp0 = protoB + (size_t)((pg0 << 4) + lc) * D_PROJ + (q << 3);
  const unsigned short* pp1 = pp0 + 16 * D_PROJ;
#pragma unroll
  for (int kk = 0; kk < 8; ++kk) {
    const v8s za = *(const v8s*)(zp  + (kk << 5));
    const v8s p0 = *(const v8s*)(pp0 + (kk << 5));
    const v8s p1 = *(const v8s*)(pp1 + (kk << 5));
    acc2[0] = __builtin_amdgcn_mfma_f32_16x16x32_bf16(za, p0, acc2[0], 0, 0, 0);
    acc2[1] = __builtin_amdgcn_mfma_f32_16x16x32_bf16(za, p1, acc2[1], 0, 0, 0);
  }

  // ---- epilogue: d^2 = ||Z||^2 + ||p||^2 - 2*dot*inv ; score = -sqrt(d^2) ----
  const float pn0 = pnorm2[(pg0 << 4) + lc];
  const float pn1 = pnorm2[(pg0 << 4) + 16 + lc];
#pragma unroll
  for (int r = 0; r < 4; ++r) {
    const int row = (rg << 4) + (q << 2) + r;
    const float inv = lds_inv[row];
    const float z2  = lds_z2[row];
    const float d0 = z2 + pn0 - 2.0f * acc2[0][r] * inv;
    const float d1 = z2 + pn1 - 2.0f * acc2[1][r] * inv;
    float* ob = out + (size_t)(row0 + row) * N_C + (pg0 << 4) + lc;
    ob[0]  = -sqrtf(fmaxf(d0, 0.0f));
    ob[16] = -sqrtf(fmaxf(d1, 0.0f));
  }
}

extern "C" void kernel_launch(void* const* d_in, const int* in_sizes, int n_in,
                              void* d_out, int out_size, void* d_ws, size_t ws_size,
                              hipStream_t stream) {
  const float* X      = (const float*)d_in[0];
  const float* protos = (const float*)d_in[1];
  const float* mean   = (const float*)d_in[2];
  const float* proj   = (const float*)d_in[3];
  float* out = (float*)d_out;

  unsigned short* projT  = (unsigned short*)d_ws;          // 256*1024 bf16 = 512 KB
  unsigned short* protoB = projT + D_PROJ * D_IN;          // 64*256  bf16 = 32 KB
  float*          pn2    = (float*)(protoB + N_C * D_PROJ);// 64 fp32
  float*          mup    = pn2 + N_C;                      // 256 fp32

  prep_kernel<<<96, 256, 0, stream>>>(proj, protos, mean, projT, protoB, pn2, mup);
  protonet_main<<<N_ROWS / BM, 512, 0, stream>>>(X, projT, protoB, pn2, mup, out);
}